// Round 19
// baseline (261.552 us; speedup 1.0000x reference)
//
#include <hip/hip_runtime.h>
#include <cstddef>

#define NPT 512      // n
#define DIM 256      // d == dy
#define KNB 16       // K neighbors
#define NK  8192     // NPT*KNB gathered rows
#define HID 512      // hidden
#define NBLK 1024    // pair_kernel blocks

constexpr float WF = 0.7f;
constexpr float UF = 0.3f;

// gather src[graph[r]] into NF (optional) and write row squared norm
__global__ __launch_bounds__(256) void gather_sq(
    const float* __restrict__ src, const int* __restrict__ graph,
    float* __restrict__ NF, float* __restrict__ sq, int cols) {
  int r = blockIdx.x;
  int t = threadIdx.x;
  int row = graph ? graph[r] : r;
  float v = (t < cols) ? src[(size_t)row * cols + t] : 0.f;
  if (NF) NF[(size_t)r * cols + t] = v;
  float s = v * v;
#pragma unroll
  for (int o = 32; o > 0; o >>= 1) s += __shfl_down(s, o);
  __shared__ float ps[4];
  int lane = t & 63, wv = t >> 6;
  if (lane == 0) ps[wv] = s;
  __syncthreads();
  if (t == 0) sq[r] = ps[0] + ps[1] + ps[2] + ps[3];
}

// unified fp32 tiled GEMM: C[M,Nd] = A[M,Kd] @ B  (+optional relu)
// transB==0: B is [Kd,Nd].  transB==1: B is [Nd,Kd] (C=A@B^T)
__global__ __launch_bounds__(256) void gemm(
    const float* __restrict__ A, const float* __restrict__ B,
    float* __restrict__ C, int M, int Kd, int Nd, int transB, int relu) {
  __shared__ float As[16][65];
  __shared__ float Bs[16][65];
  int tid = threadIdx.x;
  int m0 = blockIdx.y * 64;
  int n0 = blockIdx.x * 64;
  int tx = tid & 15, ty = tid >> 4;
  float acc[4][4] = {};
  for (int k0 = 0; k0 < Kd; k0 += 16) {
    {
      int r = tid >> 2;
      int c4 = (tid & 3) * 4;
      const float4 a = *reinterpret_cast<const float4*>(&A[(size_t)(m0 + r) * Kd + k0 + c4]);
      As[c4 + 0][r] = a.x; As[c4 + 1][r] = a.y; As[c4 + 2][r] = a.z; As[c4 + 3][r] = a.w;
      if (transB) {
        const float4 b = *reinterpret_cast<const float4*>(&B[(size_t)(n0 + r) * Kd + k0 + c4]);
        Bs[c4 + 0][r] = b.x; Bs[c4 + 1][r] = b.y; Bs[c4 + 2][r] = b.z; Bs[c4 + 3][r] = b.w;
      } else {
        int rb = tid >> 4;
        int cb = (tid & 15) * 4;
        const float4 b = *reinterpret_cast<const float4*>(&B[(size_t)(k0 + rb) * Nd + n0 + cb]);
        Bs[rb][cb + 0] = b.x; Bs[rb][cb + 1] = b.y; Bs[rb][cb + 2] = b.z; Bs[rb][cb + 3] = b.w;
      }
    }
    __syncthreads();
#pragma unroll
    for (int k = 0; k < 16; ++k) {
      float a[4], b[4];
#pragma unroll
      for (int j = 0; j < 4; ++j) { a[j] = As[k][ty + 16 * j]; b[j] = Bs[k][tx + 16 * j]; }
#pragma unroll
      for (int j = 0; j < 4; ++j)
#pragma unroll
        for (int l = 0; l < 4; ++l) acc[j][l] += a[j] * b[l];
    }
    __syncthreads();
  }
#pragma unroll
  for (int j = 0; j < 4; ++j) {
    int m = m0 + ty + 16 * j;
#pragma unroll
    for (int l = 0; l < 4; ++l) {
      int n = n0 + tx + 16 * l;
      float v = acc[j][l];
      if (relu) v = fmaxf(v, 0.f);
      C[(size_t)m * Nd + n] = v;
    }
  }
}

// per-pair term; deterministic per-block partial sums (no atomics)
__global__ __launch_bounds__(256) void pair_kernel(
    const float* __restrict__ Amat, const float* __restrict__ Bmat,
    const float* __restrict__ XX, const float* __restrict__ YY,
    const float* __restrict__ xsq, const float* __restrict__ ysq,
    const float* __restrict__ nf2, const float* __restrict__ on2,
    float* __restrict__ NB, float* __restrict__ pnb, float* __restrict__ pct) {
  int p = blockIdx.x * 256 + threadIdx.x;
  int i = p >> 9, j = p & 511;
  float xsi = xsq[i], xsj = xsq[j], ysi = ysq[i], ysj = ysq[j];
  float xxij = XX[p], yyij = YY[p];
  float xx = sqrtf(fmaxf(xsi + xsj - 2.f * xxij, 1e-12f));
  float yy = sqrtf(fmaxf(ysi + ysj - 2.f * yyij, 1e-12f));
  float nbv = fmaxf(fabsf(xx - yy), 1e-6f);
  NB[p] = nbv;

  float cx2 = WF * WF * xsi + UF * UF * xsj + 2.f * WF * UF * xxij;
  float cy2 = WF * WF * ysi + UF * UF * ysj + 2.f * WF * UF * yyij;
  const float* Ai = Amat + (size_t)i * NK + j * KNB;
  const float* Aj = Amat + (size_t)j * NK + j * KNB;
  const float* Bi = Bmat + (size_t)i * NK + j * KNB;
  const float* Bj = Bmat + (size_t)j * NK + j * KNB;
  const float* n2 = nf2 + j * KNB;
  const float* o2 = on2 + j * KNB;
  float t = 0.f;
#pragma unroll
  for (int k = 0; k < KNB; ++k) {
    float dx = sqrtf(fmaxf(cx2 + n2[k] - 2.f * (WF * Ai[k] + UF * Aj[k]), 1e-12f));
    float dv = sqrtf(fmaxf(cy2 + o2[k] - 2.f * (WF * Bi[k] + UF * Bj[k]), 1e-12f));
    t += fmaxf(fabsf(dx - dv), 1e-6f);
  }
  t *= (1.f / KNB);
  float ct = (i == j) ? 0.f : t;

  float v1 = nbv, v2 = ct;
#pragma unroll
  for (int o = 32; o > 0; o >>= 1) { v1 += __shfl_down(v1, o); v2 += __shfl_down(v2, o); }
  __shared__ float s1[4], s2[4];
  int lane = threadIdx.x & 63, wv = threadIdx.x >> 6;
  if (lane == 0) { s1[wv] = v1; s2[wv] = v2; }
  __syncthreads();
  if (threadIdx.x == 0) {
    pnb[blockIdx.x] = s1[0] + s1[1] + s1[2] + s1[3];
    pct[blockIdx.x] = s2[0] + s2[1] + s2[2] + s2[3];
  }
}

// reduce NBLK partials -> out[0], out[1]; stash ct for write_sum
__global__ __launch_bounds__(256) void finalize_scalars(
    const float* __restrict__ pnb, const float* __restrict__ pct,
    float* __restrict__ out, float* __restrict__ ct_ws) {
  int t = threadIdx.x;
  float v1 = 0.f, v2 = 0.f;
#pragma unroll
  for (int k = 0; k < NBLK / 256; ++k) {
    v1 += pnb[t + 256 * k];
    v2 += pct[t + 256 * k];
  }
#pragma unroll
  for (int o = 32; o > 0; o >>= 1) { v1 += __shfl_down(v1, o); v2 += __shfl_down(v2, o); }
  __shared__ float s1[4], s2[4];
  int lane = t & 63, wv = t >> 6;
  if (lane == 0) { s1[wv] = v1; s2[wv] = v2; }
  __syncthreads();
  if (t == 0) {
    const float inv = 1.f / (float)(NPT * NPT);
    out[0] = (s1[0] + s1[1] + s1[2] + s1[3]) * inv;
    float ct = (s2[0] + s2[1] + s2[2] + s2[3]) * inv;
    out[1] = ct;
    *ct_ws = ct;
  }
}

__global__ __launch_bounds__(256) void write_sum(
    const float* __restrict__ NB, const float* __restrict__ ct_ws,
    float* __restrict__ out) {
  int p = blockIdx.x * 256 + threadIdx.x;
  out[p] = 0.5f * (NB[p] + *ct_ws);
}

extern "C" void kernel_launch(void* const* d_in, const int* in_sizes, int n_in,
                              void* d_out, int out_size, void* d_ws, size_t ws_size,
                              hipStream_t stream) {
  const float* x       = (const float*)d_in[0];
  const float* y       = (const float*)d_in[1];
  const float* dataset = (const float*)d_in[2];
  const float* W1      = (const float*)d_in[3];
  const float* W2      = (const float*)d_in[4];
  const int*   graph   = (const int*)d_in[5];
  float* out = (float*)d_out;
  float* ws  = (float*)d_ws;

  float* NF   = ws;                  // [8192,256]
  float* H1   = ws + 2097152;        // [8192,512], later reused as Amat
  float* Amat = H1;                  // [512,8192]
  float* ON   = ws + 6291456;        // [8192,256]
  float* Bmat = ws + 8388608;        // [512,8192]
  float* XX   = ws + 12582912;       // [512,512]
  float* YY   = ws + 12845056;       // [512,512]
  float* NB   = ws + 13107200;       // [512,512]
  float* xsq  = ws + 13369344;       // [512]
  float* ysq  = ws + 13369856;       // [512]
  float* nf2  = ws + 13370368;       // [8192]
  float* on2  = ws + 13378560;       // [8192]
  float* pnb  = ws + 13386752;       // [1024]
  float* pct  = ws + 13387776;       // [1024]
  float* ctws = ws + 13388800;       // [1]

  gather_sq<<<NK, 256, 0, stream>>>(dataset, graph, NF, nf2, DIM);
  gather_sq<<<NPT, 256, 0, stream>>>(x, nullptr, nullptr, xsq, DIM);
  gather_sq<<<NPT, 256, 0, stream>>>(y, nullptr, nullptr, ysq, DIM);

  // MLP on gathered rows
  gemm<<<dim3(HID / 64, NK / 64), 256, 0, stream>>>(NF, W1, H1, NK, DIM, HID, 0, 1);
  gemm<<<dim3(DIM / 64, NK / 64), 256, 0, stream>>>(H1, W2, ON, NK, HID, DIM, 0, 0);
  gather_sq<<<NK, 256, 0, stream>>>(ON, nullptr, nullptr, on2, DIM);

  // Gram matrices
  gemm<<<dim3(NPT / 64, NPT / 64), 256, 0, stream>>>(x, x, XX, NPT, DIM, NPT, 1, 0);
  gemm<<<dim3(NPT / 64, NPT / 64), 256, 0, stream>>>(y, y, YY, NPT, DIM, NPT, 1, 0);
  gemm<<<dim3(NK / 64, NPT / 64), 256, 0, stream>>>(x, NF, Amat, NPT, DIM, NK, 1, 0);
  gemm<<<dim3(NK / 64, NPT / 64), 256, 0, stream>>>(y, ON, Bmat, NPT, DIM, NK, 1, 0);

  pair_kernel<<<NBLK, 256, 0, stream>>>(Amat, Bmat, XX, YY, xsq, ysq,
                                        nf2, on2, NB, pnb, pct);
  finalize_scalars<<<1, 256, 0, stream>>>(pnb, pct, out, ctws);
  write_sum<<<NPT * NPT / 256, 256, 0, stream>>>(NB, ctws, out + 2);
}

// Round 22
// 99.011 us; speedup vs baseline: 2.6416x; 2.6416x over previous
//
#include <hip/hip_runtime.h>
#include <cstddef>

#define NPT 512      // n
#define DIM 256      // d == dy
#define KNB 16       // K neighbors
#define NK  8192     // NPT*KNB gathered rows
#define HID 512      // hidden
#define NBLK 1024    // pair_kernel blocks

typedef unsigned short u16;
typedef unsigned int u32;
typedef __bf16 bf16x8 __attribute__((ext_vector_type(8)));
typedef float f32x4 __attribute__((ext_vector_type(4)));
typedef unsigned short us8 __attribute__((ext_vector_type(8)));

constexpr float WF = 0.7f;
constexpr float UF = 0.3f;

__device__ inline u16 f2b(float x) {
  u32 u = __float_as_uint(x);
  u32 r = u + 0x7FFFu + ((u >> 16) & 1u);   // RNE
  return (u16)(r >> 16);
}
__device__ inline float b2f(u16 h) { return __uint_as_float(((u32)h) << 16); }

// gather(+convert to bf16)(+row sqnorm). src is fp32 or bf16 (one non-null).
__global__ __launch_bounds__(256) void prep(
    const float* __restrict__ srcf, const u16* __restrict__ srcb,
    const int* __restrict__ graph, u16* __restrict__ dst,
    float* __restrict__ sq) {
  int r = blockIdx.x, t = threadIdx.x;
  int row = graph ? graph[r] : r;
  float v = srcf ? srcf[(size_t)row * DIM + t] : b2f(srcb[(size_t)row * DIM + t]);
  if (dst) dst[(size_t)r * DIM + t] = f2b(v);
  float s = v * v;
#pragma unroll
  for (int o = 32; o > 0; o >>= 1) s += __shfl_down(s, o);
  __shared__ float ps[4];
  if ((t & 63) == 0) ps[t >> 6] = s;
  __syncthreads();
  if (t == 0) sq[r] = ps[0] + ps[1] + ps[2] + ps[3];
}

// out[n][k] = bf16(W[k][n])  (transpose + convert; small matrices, one-shot)
__global__ __launch_bounds__(256) void tconv(
    const float* __restrict__ W, u16* __restrict__ out, int Kd, int Nd) {
  int n = blockIdx.x;
  for (int k = threadIdx.x; k < Kd; k += 256)
    out[(size_t)n * Kd + k] = f2b(W[(size_t)k * Nd + n]);
}

// bf16 MFMA NT GEMM: C[M,N] = A[M,K] @ B[N,K]^T  (+relu). Output fp32 (Cf) or bf16 (Cb).
// 64x64 tile, BK=64, 256 threads = 4 waves; wave w -> rows [w*16, w*16+16).
__global__ __launch_bounds__(256) void gemm_bf16(
    const u16* __restrict__ A, const u16* __restrict__ B,
    float* __restrict__ Cf, u16* __restrict__ Cb,
    int M, int K, int N, int relu) {
  __shared__ u16 As[64][72];   // +8 pad: row stride 144B -> only free 2-way conflicts
  __shared__ u16 Bs[64][72];
  int tid = threadIdx.x;
  int n0 = blockIdx.x * 64, m0 = blockIdx.y * 64;
  int lane = tid & 63, wave = tid >> 6;
  int ar = lane & 15;          // A-row / B-col within fragment
  int ks = lane >> 4;          // k-subgroup (0..3), 8 elements each
  int sr = tid >> 2, sc = (tid & 3) * 16;  // staging: row, 16-col group
  f32x4 acc[4] = {};
  for (int k0 = 0; k0 < K; k0 += 64) {
    const us8* ga = reinterpret_cast<const us8*>(&A[(size_t)(m0 + sr) * K + k0 + sc]);
    const us8* gb = reinterpret_cast<const us8*>(&B[(size_t)(n0 + sr) * K + k0 + sc]);
    *reinterpret_cast<us8*>(&As[sr][sc])     = ga[0];
    *reinterpret_cast<us8*>(&As[sr][sc + 8]) = ga[1];
    *reinterpret_cast<us8*>(&Bs[sr][sc])     = gb[0];
    *reinterpret_cast<us8*>(&Bs[sr][sc + 8]) = gb[1];
    __syncthreads();
#pragma unroll
    for (int kk = 0; kk < 64; kk += 32) {
      bf16x8 a = *reinterpret_cast<const bf16x8*>(&As[wave * 16 + ar][kk + ks * 8]);
#pragma unroll
      for (int f = 0; f < 4; ++f) {
        bf16x8 b = *reinterpret_cast<const bf16x8*>(&Bs[f * 16 + ar][kk + ks * 8]);
        acc[f] = __builtin_amdgcn_mfma_f32_16x16x32_bf16(a, b, acc[f], 0, 0, 0);
      }
    }
    __syncthreads();
  }
  // C/D layout: col = lane&15, row = (lane>>4)*4 + reg   [m89-verified]
#pragma unroll
  for (int f = 0; f < 4; ++f)
#pragma unroll
    for (int r = 0; r < 4; ++r) {
      int m = m0 + wave * 16 + ks * 4 + r;
      int n = n0 + f * 16 + ar;
      float v = acc[f][r];
      if (relu) v = fmaxf(v, 0.f);
      if (Cf) Cf[(size_t)m * N + n] = v;
      else    Cb[(size_t)m * N + n] = f2b(v);
    }
}

// per-pair term; deterministic per-block partial sums (no atomics)
__global__ __launch_bounds__(256) void pair_kernel(
    const u16* __restrict__ Am, const u16* __restrict__ Bm,
    const float* __restrict__ XX, const float* __restrict__ YY,
    const float* __restrict__ xsq, const float* __restrict__ ysq,
    const float* __restrict__ nf2, const float* __restrict__ on2,
    float* __restrict__ NB, float* __restrict__ pnb, float* __restrict__ pct) {
  int p = blockIdx.x * 256 + threadIdx.x;
  int i = p >> 9, j = p & 511;
  float xsi = xsq[i], xsj = xsq[j], ysi = ysq[i], ysj = ysq[j];
  float xxij = XX[p], yyij = YY[p];
  float xx, yy;
  if (i == j) {            // exact: dist(a,a) = sqrt(clip(0)) = 1e-6 in reference;
    xx = 1e-6f;            // bf16 Gram error (~±0.1) would otherwise give sqrt(0.1)≈0.3
    yy = 1e-6f;
  } else {
    xx = sqrtf(fmaxf(xsi + xsj - 2.f * xxij, 1e-12f));
    yy = sqrtf(fmaxf(ysi + ysj - 2.f * yyij, 1e-12f));
  }
  float nbv = fmaxf(fabsf(xx - yy), 1e-6f);
  NB[p] = nbv;

  float cx2 = WF * WF * xsi + UF * UF * xsj + 2.f * WF * UF * xxij;
  float cy2 = WF * WF * ysi + UF * UF * ysj + 2.f * WF * UF * yyij;
  const u16* Ai = Am + (size_t)i * NK + j * KNB;
  const u16* Aj = Am + (size_t)j * NK + j * KNB;
  const u16* Bi = Bm + (size_t)i * NK + j * KNB;
  const u16* Bj = Bm + (size_t)j * NK + j * KNB;
  const float* n2 = nf2 + j * KNB;
  const float* o2 = on2 + j * KNB;
  float t = 0.f;
#pragma unroll
  for (int k = 0; k < KNB; ++k) {
    float dx = sqrtf(fmaxf(cx2 + n2[k] - 2.f * (WF * b2f(Ai[k]) + UF * b2f(Aj[k])), 1e-12f));
    float dv = sqrtf(fmaxf(cy2 + o2[k] - 2.f * (WF * b2f(Bi[k]) + UF * b2f(Bj[k])), 1e-12f));
    t += fmaxf(fabsf(dx - dv), 1e-6f);
  }
  t *= (1.f / KNB);
  float ct = (i == j) ? 0.f : t;

  float v1 = nbv, v2 = ct;
#pragma unroll
  for (int o = 32; o > 0; o >>= 1) { v1 += __shfl_down(v1, o); v2 += __shfl_down(v2, o); }
  __shared__ float s1[4], s2[4];
  int lane = threadIdx.x & 63, wv = threadIdx.x >> 6;
  if (lane == 0) { s1[wv] = v1; s2[wv] = v2; }
  __syncthreads();
  if (threadIdx.x == 0) {
    pnb[blockIdx.x] = s1[0] + s1[1] + s1[2] + s1[3];
    pct[blockIdx.x] = s2[0] + s2[1] + s2[2] + s2[3];
  }
}

__global__ __launch_bounds__(256) void finalize_scalars(
    const float* __restrict__ pnb, const float* __restrict__ pct,
    float* __restrict__ out, float* __restrict__ ct_ws) {
  int t = threadIdx.x;
  float v1 = 0.f, v2 = 0.f;
#pragma unroll
  for (int k = 0; k < NBLK / 256; ++k) {
    v1 += pnb[t + 256 * k];
    v2 += pct[t + 256 * k];
  }
#pragma unroll
  for (int o = 32; o > 0; o >>= 1) { v1 += __shfl_down(v1, o); v2 += __shfl_down(v2, o); }
  __shared__ float s1[4], s2[4];
  int lane = t & 63, wv = t >> 6;
  if (lane == 0) { s1[wv] = v1; s2[wv] = v2; }
  __syncthreads();
  if (t == 0) {
    const float inv = 1.f / (float)(NPT * NPT);
    out[0] = (s1[0] + s1[1] + s1[2] + s1[3]) * inv;
    float ct = (s2[0] + s2[1] + s2[2] + s2[3]) * inv;
    out[1] = ct;
    *ct_ws = ct;
  }
}

__global__ __launch_bounds__(256) void write_sum(
    const float* __restrict__ NB, const float* __restrict__ ct_ws,
    float* __restrict__ out) {
  int p = blockIdx.x * 256 + threadIdx.x;
  out[p] = 0.5f * (NB[p] + *ct_ws);
}

extern "C" void kernel_launch(void* const* d_in, const int* in_sizes, int n_in,
                              void* d_out, int out_size, void* d_ws, size_t ws_size,
                              hipStream_t stream) {
  const float* x       = (const float*)d_in[0];
  const float* y       = (const float*)d_in[1];
  const float* dataset = (const float*)d_in[2];
  const float* W1      = (const float*)d_in[3];
  const float* W2      = (const float*)d_in[4];
  const int*   graph   = (const int*)d_in[5];
  float* out = (float*)d_out;
  float* ws  = (float*)d_ws;

  // workspace (float offsets); u16 buffers occupy count/2 floats
  u16* NFb   = (u16*)(ws);                    // [8192*256] bf16
  u16* xb    = (u16*)(ws + 1048576);          // [512*256]
  u16* yb    = (u16*)(ws + 1114112);
  u16* W1Tb  = (u16*)(ws + 1179648);          // [512][256]
  u16* W2Tb  = (u16*)(ws + 1245184);          // [256][512]
  u16* H1b   = (u16*)(ws + 1310720);          // [8192*512]
  u16* ONb   = (u16*)(ws + 3407872);          // [8192*256]
  u16* Amb   = (u16*)(ws + 4456448);          // [512*8192]
  u16* Bmb   = (u16*)(ws + 6553600);          // [512*8192]
  float* XX  = ws + 8650752;                  // [512*512]
  float* YY  = ws + 8912896;
  float* NB  = ws + 9175040;
  float* xsq = ws + 9437184;                  // [512]
  float* ysq = ws + 9437696;
  float* nf2 = ws + 9438208;                  // [8192]
  float* on2 = ws + 9446400;
  float* pnb = ws + 9454592;                  // [1024]
  float* pct = ws + 9455616;
  float* ctws= ws + 9456640;                  // [1]

  prep<<<NPT, 256, 0, stream>>>(x, nullptr, nullptr, xb, xsq);
  prep<<<NPT, 256, 0, stream>>>(y, nullptr, nullptr, yb, ysq);
  prep<<<NK,  256, 0, stream>>>(dataset, nullptr, graph, NFb, nf2);
  tconv<<<HID, 256, 0, stream>>>(W1, W1Tb, DIM, HID);   // W1[256,512] -> [512,256]
  tconv<<<DIM, 256, 0, stream>>>(W2, W2Tb, HID, DIM);   // W2[512,256] -> [256,512]

  // MLP: H1 = relu(NF @ W1) -> bf16 ; ON = H1 @ W2 -> bf16
  gemm_bf16<<<dim3(HID / 64, NK / 64), 256, 0, stream>>>(NFb, W1Tb, nullptr, H1b, NK, DIM, HID, 1);
  gemm_bf16<<<dim3(DIM / 64, NK / 64), 256, 0, stream>>>(H1b, W2Tb, nullptr, ONb, NK, HID, DIM, 0);
  prep<<<NK, 256, 0, stream>>>(nullptr, ONb, nullptr, nullptr, on2);

  // Gram matrices (fp32 out) and cross matrices (bf16 out)
  gemm_bf16<<<dim3(NPT / 64, NPT / 64), 256, 0, stream>>>(xb, xb, XX, nullptr, NPT, DIM, NPT, 0);
  gemm_bf16<<<dim3(NPT / 64, NPT / 64), 256, 0, stream>>>(yb, yb, YY, nullptr, NPT, DIM, NPT, 0);
  gemm_bf16<<<dim3(NK / 64, NPT / 64), 256, 0, stream>>>(xb, NFb, nullptr, Amb, NPT, DIM, NK, 0);
  gemm_bf16<<<dim3(NK / 64, NPT / 64), 256, 0, stream>>>(yb, ONb, nullptr, Bmb, NPT, DIM, NK, 0);

  pair_kernel<<<NBLK, 256, 0, stream>>>(Amb, Bmb, XX, YY, xsq, ysq,
                                        nf2, on2, NB, pnb, pct);
  finalize_scalars<<<1, 256, 0, stream>>>(pnb, pct, out, ctws);
  write_sum<<<NPT * NPT / 256, 256, 0, stream>>>(NB, ctws, out + 2);
}